// Round 2
// baseline (250.924 us; speedup 1.0000x reference)
//
#include <hip/hip_runtime.h>
#include <hip/hip_fp16.h>
#include <math.h>

#define N_NODES  100000
#define N_HID    128
#define N_ETYPES 10
#define N_EDGES  100000
#define TOT_EDGES (N_ETYPES * N_EDGES)   // 1,000,000

#define NB       3125    // src buckets: src>>5 (32 nodes = 8KB of rows per bucket)
#define CPAD     16      // pad counters to 64B to avoid same-line atomic serialization

#define EDGES_PER_HW 4   // legacy fallback kernels only

typedef __attribute__((ext_vector_type(2))) _Float16 h2v;

#if defined(__has_builtin)
#if __has_builtin(__builtin_amdgcn_fdot2)
#define HAVE_FDOT2 1
#endif
#endif

__device__ __forceinline__ float dot2acc(h2v a, h2v b, float c) {
#ifdef HAVE_FDOT2
    return __builtin_amdgcn_fdot2(a, b, c, false);
#else
    return c + (float)a.x * (float)b.x + (float)a.y * (float)b.y;
#endif
}

// VALU-only cross-lane reduce within 16-lane row groups (no DS pipe).
template<int CTRL>
__device__ __forceinline__ float ror_add(float p) {
    int r = __builtin_amdgcn_update_dpp(0, __float_as_int(p), CTRL, 0xF, 0xF, true);
    return p + __int_as_float(r);
}
__device__ __forceinline__ float row16_sum(float p) {
    p = ror_add<0x121>(p);  // row_ror:1
    p = ror_add<0x122>(p);  // row_ror:2
    p = ror_add<0x124>(p);  // row_ror:4
    p = ror_add<0x128>(p);  // row_ror:8
    return p;
}

__device__ __forceinline__ float dot_row(uint4 a, uint4 b, uint4 w) {
    union { uint4 u; h2v p[4]; } ua, ub, uw;
    ua.u = a; ub.u = b; uw.u = w;
    float p = dot2acc(ua.p[0], (h2v)(uw.p[0] * ub.p[0]), 0.0f);
    p = dot2acc(ua.p[1], (h2v)(uw.p[1] * ub.p[1]), p);
    p = dot2acc(ua.p[2], (h2v)(uw.p[2] * ub.p[2]), p);
    p = dot2acc(ua.p[3], (h2v)(uw.p[3] * ub.p[3]), p);
    return p;
}

// ---------------- pass 1: h -> fp16; Wr16[t] = fp16(W[rel[t]]); zero hist ----------------
__global__ __launch_bounds__(256) void convert_kernel(
    const float* __restrict__ h, const float* __restrict__ W,
    const int*   __restrict__ rel,
    __half* __restrict__ h16, __half* __restrict__ Wr16,
    int* __restrict__ hist)
{
    const size_t i = ((size_t)blockIdx.x * 256 + threadIdx.x) * 8;
    const float4 f0 = *(const float4*)(h + i);
    const float4 f1 = *(const float4*)(h + i + 4);
    union { uint4 u; __half2 p[4]; } pk;
    pk.p[0] = __floats2half2_rn(f0.x, f0.y);
    pk.p[1] = __floats2half2_rn(f0.z, f0.w);
    pk.p[2] = __floats2half2_rn(f1.x, f1.y);
    pk.p[3] = __floats2half2_rn(f1.z, f1.w);
    *(uint4*)(h16 + i) = pk.u;

    // zero the 51200-int histogram region (blocks 0..49)
    if (blockIdx.x < 50) {
        int* p = hist + blockIdx.x * 1024;
        for (int k = threadIdx.x; k < 1024; k += 256) p[k] = 0;
    }

    // Wr16: relation-resolved fp16 W rows (10x128)
    if (blockIdx.x == 0 && threadIdx.x < (N_ETYPES * N_HID / 8)) {
        const int j = threadIdx.x * 8;       // [0,1280)
        const int t = j >> 7;
        const int c = j & (N_HID - 1);
        const int r = rel[t];
        const float4 g0 = *(const float4*)(W + (size_t)r * N_HID + c);
        const float4 g1 = *(const float4*)(W + (size_t)r * N_HID + c + 4);
        union { uint4 u; __half2 p[4]; } pw;
        pw.p[0] = __floats2half2_rn(g0.x, g0.y);
        pw.p[1] = __floats2half2_rn(g0.z, g0.w);
        pw.p[2] = __floats2half2_rn(g1.x, g1.y);
        pw.p[3] = __floats2half2_rn(g1.z, g1.w);
        *(uint4*)(Wr16 + j) = pw.u;
    }
}

// ---------------- pass 2: histogram of src buckets ----------------
__global__ __launch_bounds__(256) void hist_kernel(
    const int* __restrict__ src, int* __restrict__ hist)
{
    const int e0 = (blockIdx.x * 256 + threadIdx.x) * 8;
    if (e0 >= TOT_EDGES) return;
    const int4 a = *(const int4*)(src + e0);
    const int4 b = *(const int4*)(src + e0 + 4);
    atomicAdd(&hist[(a.x >> 5) * CPAD], 1);
    atomicAdd(&hist[(a.y >> 5) * CPAD], 1);
    atomicAdd(&hist[(a.z >> 5) * CPAD], 1);
    atomicAdd(&hist[(a.w >> 5) * CPAD], 1);
    atomicAdd(&hist[(b.x >> 5) * CPAD], 1);
    atomicAdd(&hist[(b.y >> 5) * CPAD], 1);
    atomicAdd(&hist[(b.z >> 5) * CPAD], 1);
    atomicAdd(&hist[(b.w >> 5) * CPAD], 1);
}

// ---------------- pass 3: exclusive prefix over NB counters ----------------
__global__ __launch_bounds__(1024) void scan_kernel(
    const int* __restrict__ hist, int* __restrict__ cursor)
{
    __shared__ int lds[1024];
    const int t = threadIdx.x;
    int v[4]; int s = 0;
    #pragma unroll
    for (int k = 0; k < 4; ++k) {
        const int i = t * 4 + k;
        v[k] = (i < NB) ? hist[i * CPAD] : 0;
        s += v[k];
    }
    lds[t] = s;
    for (int o = 1; o < 1024; o <<= 1) {
        __syncthreads();
        const int x = (t >= o) ? lds[t - o] : 0;
        __syncthreads();
        lds[t] += x;
    }
    int excl = lds[t] - s;
    #pragma unroll
    for (int k = 0; k < 4; ++k) {
        const int i = t * 4 + k;
        if (i < NB) { cursor[i * CPAD] = excl; excl += v[k]; }
    }
}

// ---------------- pass 4: scatter edges into src-bucket order ----------------
// record: lo = src(17) | dst[14:0]<<17 ; hi = dst>>15 (2) | ety<<2 (4) | off<<6 (17)
__global__ __launch_bounds__(256) void scatter_kernel(
    const int* __restrict__ src, const int* __restrict__ dst,
    int* __restrict__ cursor, uint2* __restrict__ rec)
{
    const int e0 = (blockIdx.x * 256 + threadIdx.x) * 8;
    if (e0 >= TOT_EDGES) return;
    const int4 s0 = *(const int4*)(src + e0);
    const int4 s1 = *(const int4*)(src + e0 + 4);
    const int4 d0 = *(const int4*)(dst + e0);
    const int4 d1 = *(const int4*)(dst + e0 + 4);
    const int ss[8] = { s0.x, s0.y, s0.z, s0.w, s1.x, s1.y, s1.z, s1.w };
    const int dd[8] = { d0.x, d0.y, d0.z, d0.w, d1.x, d1.y, d1.z, d1.w };
    #pragma unroll
    for (int k = 0; k < 8; ++k) {
        const int e   = e0 + k;
        const int ety = (int)(((unsigned long long)(unsigned)e * 1407374884ULL) >> 47);
        const int off = e - ety * N_EDGES;
        const int pos = atomicAdd(&cursor[(ss[k] >> 5) * CPAD], 1);
        const unsigned lo = (unsigned)ss[k] | ((unsigned)dd[k] << 17);
        const unsigned hi = ((unsigned)dd[k] >> 15) | ((unsigned)ety << 2) | ((unsigned)off << 6);
        rec[pos] = make_uint2(lo, hi);
    }
}

// ---------------- pass 5: gather + dot + sigmoid over src-sorted records ----------------
__global__ __launch_bounds__(256) void score_kernel(
    const __half* __restrict__ h16,
    const __half* __restrict__ Wr16,
    const uint2*  __restrict__ rec,
    float*        __restrict__ out)
{
    const int lane = threadIdx.x & 63;
    const int g    = lane >> 4;    // group = edge within slot
    const int gl   = lane & 15;
    const int wid  = threadIdx.x >> 6;
    const int p0i  = blockIdx.x * 32 + wid * 8;   // 8 edges per wave

    // broadcast record loads (16 lanes same addr)
    const uint2 r0 = rec[p0i + g];
    const uint2 r1 = rec[p0i + 4 + g];

    const unsigned col = (unsigned)gl << 3;   // 8 halfs (16B) per lane

    const unsigned sA = r0.x & 131071u;
    const unsigned dA = ((r0.x >> 17) | (r0.y << 15)) & 131071u;
    const unsigned tA = (r0.y >> 2) & 15u;
    const unsigned oA = (r0.y >> 6) & 131071u;
    const unsigned sB = r1.x & 131071u;
    const unsigned dB = ((r1.x >> 17) | (r1.y << 15)) & 131071u;
    const unsigned tB = (r1.y >> 2) & 15u;
    const unsigned oB = (r1.y >> 6) & 131071u;

    const uint4 W0 = *(const uint4*)(Wr16 + ((tA << 7) + col));
    const uint4 W1 = *(const uint4*)(Wr16 + ((tB << 7) + col));
    const uint4 A0 = *(const uint4*)(h16 + ((sA << 7) + col));
    const uint4 B0 = *(const uint4*)(h16 + ((dA << 7) + col));
    const uint4 A1 = *(const uint4*)(h16 + ((sB << 7) + col));
    const uint4 B1 = *(const uint4*)(h16 + ((dB << 7) + col));

    float p0 = dot_row(A0, B0, W0);
    float p1 = dot_row(A1, B1, W1);
    p0 = row16_sum(p0);
    p1 = row16_sum(p1);

    if (gl < 2) {
        const float res = gl ? p1 : p0;
        const int   idx = gl ? (int)(tB * N_EDGES + oB) : (int)(tA * N_EDGES + oA);
        out[idx] = 1.0f / (1.0f + __expf(-res));   // plain store: let L2 merge scattered 4B writes
    }
}

// ---------------- legacy direct-f16 path (if ws too small for sort buffers) ----------------
__global__ __launch_bounds__(256) void convert_legacy_kernel(
    const float* __restrict__ h, const float* __restrict__ W,
    __half* __restrict__ h16, __half* __restrict__ W16)
{
    const size_t i = ((size_t)blockIdx.x * 256 + threadIdx.x) * 8;
    const float4 f0 = *(const float4*)(h + i);
    const float4 f1 = *(const float4*)(h + i + 4);
    union { uint4 u; __half2 p[4]; } pk;
    pk.p[0] = __floats2half2_rn(f0.x, f0.y);
    pk.p[1] = __floats2half2_rn(f0.z, f0.w);
    pk.p[2] = __floats2half2_rn(f1.x, f1.y);
    pk.p[3] = __floats2half2_rn(f1.z, f1.w);
    *(uint4*)(h16 + i) = pk.u;
    if (blockIdx.x == 0 && threadIdx.x < (N_ETYPES * N_HID / 8)) {
        const size_t j = (size_t)threadIdx.x * 8;
        const float4 g0 = *(const float4*)(W + j);
        const float4 g1 = *(const float4*)(W + j + 4);
        union { uint4 u; __half2 p[4]; } pw;
        pw.p[0] = __floats2half2_rn(g0.x, g0.y);
        pw.p[1] = __floats2half2_rn(g0.z, g0.w);
        pw.p[2] = __floats2half2_rn(g1.x, g1.y);
        pw.p[3] = __floats2half2_rn(g1.z, g1.w);
        *(uint4*)(W16 + j) = pw.u;
    }
}

__global__ __launch_bounds__(256) void distmult_score_f16_kernel(
    const __half* __restrict__ h16,
    const __half* __restrict__ W16,
    const int*    __restrict__ src,
    const int*    __restrict__ dst,
    const int*    __restrict__ rel,
    float*        __restrict__ out)
{
    const int t    = blockIdx.y;
    const int lane = threadIdx.x & 63;
    const int g    = lane >> 4;
    const int gl   = lane & 15;
    const int wid  = threadIdx.x >> 6;
    const int r = rel[t];
    union { uint4 u; h2v p[4]; } uw;
    uw.u = ((const uint4*)(W16 + (size_t)r * N_HID))[gl];
    const int base = t * N_EDGES;
    const int e0   = (blockIdx.x * 4 + wid) * 8;
    const int* sp = src + base + e0 + g;
    const int* dp = dst + base + e0 + g;
    const int s0 = sp[0], s1 = sp[4], d0 = dp[0], d1 = dp[4];
    const unsigned col = (unsigned)gl << 3;
    const uint4 A0 = *(const uint4*)(h16 + (((unsigned)s0 << 7) + col));
    const uint4 B0 = *(const uint4*)(h16 + (((unsigned)d0 << 7) + col));
    const uint4 A1 = *(const uint4*)(h16 + (((unsigned)s1 << 7) + col));
    const uint4 B1 = *(const uint4*)(h16 + (((unsigned)d1 << 7) + col));
    float p0 = dot_row(A0, B0, uw.u);
    float p1 = dot_row(A1, B1, uw.u);
    p0 = row16_sum(p0);
    p1 = row16_sum(p1);
    if (gl < 2) {
        const float res = gl ? p1 : p0;
        const int e = e0 + g + (gl << 2);
        out[base + e] = 1.0f / (1.0f + __expf(-res));
    }
}

// ---------------- fp32 fallback (no workspace) ----------------
__global__ __launch_bounds__(256) void distmult_score_f32_kernel(
    const float* __restrict__ h,
    const float* __restrict__ W,
    const int*   __restrict__ src,
    const int*   __restrict__ dst,
    const int*   __restrict__ rel,
    float*       __restrict__ out)
{
    const int t    = blockIdx.y;
    const int lane = threadIdx.x & 31;
    const int hw   = (blockIdx.x << 3) + (threadIdx.x >> 5);
    const int r = rel[t];
    const float4 w4 = ((const float4*)(W + (size_t)r * N_HID))[lane];
    const long base = (long)t * N_EDGES;
    const int  e0   = hw * EDGES_PER_HW;
    float res = 0.0f;
    #pragma unroll
    for (int k = 0; k < EDGES_PER_HW; ++k) {
        const int e = e0 + k;
        const int s = src[base + e];
        const int d = dst[base + e];
        const float4 a = ((const float4*)(h + (size_t)s * N_HID))[lane];
        const float4 b = ((const float4*)(h + (size_t)d * N_HID))[lane];
        float p = a.x * w4.x * b.x + a.y * w4.y * b.y
                + a.z * w4.z * b.z + a.w * w4.w * b.w;
        p += __shfl_xor(p, 16, 64);
        p += __shfl_xor(p, 8, 64);
        p += __shfl_xor(p, 4, 64);
        p += __shfl_xor(p, 2, 64);
        p += __shfl_xor(p, 1, 64);
        if (lane == k) res = p;
    }
    if (lane < EDGES_PER_HW) {
        out[base + e0 + lane] = 1.0f / (1.0f + __expf(-res));
    }
}

extern "C" void kernel_launch(void* const* d_in, const int* in_sizes, int n_in,
                              void* d_out, int out_size, void* d_ws, size_t ws_size,
                              hipStream_t stream) {
    const float* h   = (const float*)d_in[0];
    const float* W   = (const float*)d_in[1];
    const int*   src = (const int*)d_in[2];
    const int*   dst = (const int*)d_in[3];
    const int*   rel = (const int*)d_in[4];
    float*       out = (float*)d_out;

    const size_t h16_bytes  = (size_t)N_NODES * N_HID * sizeof(__half);  // 25,600,000
    const size_t rec_bytes  = (size_t)TOT_EDGES * 8;                     //  8,000,000
    const size_t wr16_bytes = 4096;
    const size_t cnt_bytes  = 51200 * sizeof(int);                       //    204,800
    const size_t need_full  = h16_bytes + rec_bytes + wr16_bytes + 2 * cnt_bytes;
    const size_t need_f16   = h16_bytes + (size_t)N_ETYPES * N_HID * sizeof(__half);

    if (ws_size >= need_full) {
        char* w = (char*)d_ws;
        __half* h16   = (__half*)w;              w += h16_bytes;
        uint2*  rec   = (uint2*)w;               w += rec_bytes;
        __half* Wr16  = (__half*)w;              w += wr16_bytes;
        int*    hist  = (int*)w;                 w += cnt_bytes;
        int*    cursor= (int*)w;

        convert_kernel<<<(int)(((size_t)N_NODES * N_HID) / (256 * 8)), 256, 0, stream>>>(
            h, W, rel, h16, Wr16, hist);
        const int nblk = (TOT_EDGES + 2047) / 2048;   // 489
        hist_kernel<<<nblk, 256, 0, stream>>>(src, hist);
        scan_kernel<<<1, 1024, 0, stream>>>(hist, cursor);
        scatter_kernel<<<nblk, 256, 0, stream>>>(src, dst, cursor, rec);
        score_kernel<<<TOT_EDGES / 32, 256, 0, stream>>>(h16, Wr16, rec, out);
    } else if (ws_size >= need_f16) {
        __half* h16 = (__half*)d_ws;
        __half* W16 = h16 + (size_t)N_NODES * N_HID;
        convert_legacy_kernel<<<(int)(((size_t)N_NODES * N_HID) / (256 * 8)), 256, 0, stream>>>(
            h, W, h16, W16);
        dim3 grid(N_EDGES / 32, N_ETYPES);
        distmult_score_f16_kernel<<<grid, 256, 0, stream>>>(h16, W16, src, dst, rel, out);
    } else {
        dim3 grid(N_EDGES / (8 * EDGES_PER_HW), N_ETYPES);
        distmult_score_f32_kernel<<<grid, 256, 0, stream>>>(h, W, src, dst, rel, out);
    }
}

// Round 3
// 156.198 us; speedup vs baseline: 1.6064x; 1.6064x over previous
//
#include <hip/hip_runtime.h>
#include <hip/hip_fp16.h>
#include <math.h>

#define N_NODES  100000
#define N_HID    128
#define N_ETYPES 10
#define N_EDGES  100000
#define TOT_EDGES (N_ETYPES * N_EDGES)   // 1,000,000

#define NSLICE    64        // dst slices: slice = dst/1562.5 (0.4 MB of rows each)
#define SLICE_CAP 16384     // fixed region per slice; mean 15625, sd ~124 -> 6σ safe
#define EPB_SC    2048      // edges per scatter block

#define EDGES_PER_HW 4      // legacy fallback only

typedef __attribute__((ext_vector_type(2))) _Float16 h2v;

#if defined(__has_builtin)
#if __has_builtin(__builtin_amdgcn_fdot2)
#define HAVE_FDOT2 1
#endif
#endif

__device__ __forceinline__ float dot2acc(h2v a, h2v b, float c) {
#ifdef HAVE_FDOT2
    return __builtin_amdgcn_fdot2(a, b, c, false);
#else
    return c + (float)a.x * (float)b.x + (float)a.y * (float)b.y;
#endif
}

// VALU-only cross-lane reduce within 16-lane row groups (no DS pipe).
template<int CTRL>
__device__ __forceinline__ float ror_add(float p) {
    int r = __builtin_amdgcn_update_dpp(0, __float_as_int(p), CTRL, 0xF, 0xF, true);
    return p + __int_as_float(r);
}
__device__ __forceinline__ float row16_sum(float p) {
    p = ror_add<0x121>(p);  // row_ror:1
    p = ror_add<0x122>(p);  // row_ror:2
    p = ror_add<0x124>(p);  // row_ror:4
    p = ror_add<0x128>(p);  // row_ror:8
    return p;
}

__device__ __forceinline__ float dot_row(uint4 a, uint4 b, uint4 w) {
    union { uint4 u; h2v p[4]; } ua, ub, uw;
    ua.u = a; ub.u = b; uw.u = w;
    float p = dot2acc(ua.p[0], (h2v)(uw.p[0] * ub.p[0]), 0.0f);
    p = dot2acc(ua.p[1], (h2v)(uw.p[1] * ub.p[1]), p);
    p = dot2acc(ua.p[2], (h2v)(uw.p[2] * ub.p[2]), p);
    p = dot2acc(ua.p[3], (h2v)(uw.p[3] * ub.p[3]), p);
    return p;
}

// ---------------- pass 1: h -> fp16; Wr16[t] = fp16(W[rel[t]]); init cursors ----------------
__global__ __launch_bounds__(256) void convert_kernel(
    const float* __restrict__ h, const float* __restrict__ W,
    const int*   __restrict__ rel,
    __half* __restrict__ h16, __half* __restrict__ Wr16,
    int* __restrict__ cursor)
{
    const size_t i = ((size_t)blockIdx.x * 256 + threadIdx.x) * 8;
    const float4 f0 = *(const float4*)(h + i);
    const float4 f1 = *(const float4*)(h + i + 4);
    union { uint4 u; __half2 p[4]; } pk;
    pk.p[0] = __floats2half2_rn(f0.x, f0.y);
    pk.p[1] = __floats2half2_rn(f0.z, f0.w);
    pk.p[2] = __floats2half2_rn(f1.x, f1.y);
    pk.p[3] = __floats2half2_rn(f1.z, f1.w);
    *(uint4*)(h16 + i) = pk.u;

    if (blockIdx.x == 0) {
        if (threadIdx.x < NSLICE) cursor[threadIdx.x] = threadIdx.x * SLICE_CAP;
        // Wr16: relation-resolved fp16 W rows (10x128)
        if (threadIdx.x < (N_ETYPES * N_HID / 8)) {
            const int j = threadIdx.x * 8;       // [0,1280)
            const int t = j >> 7;
            const int c = j & (N_HID - 1);
            const int r = rel[t];
            const float4 g0 = *(const float4*)(W + (size_t)r * N_HID + c);
            const float4 g1 = *(const float4*)(W + (size_t)r * N_HID + c + 4);
            union { uint4 u; __half2 p[4]; } pw;
            pw.p[0] = __floats2half2_rn(g0.x, g0.y);
            pw.p[1] = __floats2half2_rn(g0.z, g0.w);
            pw.p[2] = __floats2half2_rn(g1.x, g1.y);
            pw.p[3] = __floats2half2_rn(g1.z, g1.w);
            *(uint4*)(Wr16 + j) = pw.u;
        }
    }
}

// ---------------- pass 2: single-pass bucketed scatter into 64 dst-slice regions --------
// record: lo = src(17) | dst[14:0]<<17 ; hi = dst>>15 (2) | ety<<2 (4) | off<<6 (17)
__global__ __launch_bounds__(256) void scatter_kernel(
    const int* __restrict__ src, const int* __restrict__ dst,
    int* __restrict__ cursor, uint2* __restrict__ rec)
{
    __shared__ int lcnt[NSLICE];
    __shared__ int lbase[NSLICE];
    const int tid = threadIdx.x;
    if (tid < NSLICE) lcnt[tid] = 0;
    __syncthreads();

    const int e0 = blockIdx.x * EPB_SC + tid * 8;
    const bool active = (e0 < TOT_EDGES);   // TOT % 8 == 0 -> no straddle

    int ss[8], dd[8], sl[8];
    if (active) {
        const int4 s0 = *(const int4*)(src + e0);
        const int4 s1 = *(const int4*)(src + e0 + 4);
        const int4 d0 = *(const int4*)(dst + e0);
        const int4 d1 = *(const int4*)(dst + e0 + 4);
        ss[0]=s0.x; ss[1]=s0.y; ss[2]=s0.z; ss[3]=s0.w;
        ss[4]=s1.x; ss[5]=s1.y; ss[6]=s1.z; ss[7]=s1.w;
        dd[0]=d0.x; dd[1]=d0.y; dd[2]=d0.z; dd[3]=d0.w;
        dd[4]=d1.x; dd[5]=d1.y; dd[6]=d1.z; dd[7]=d1.w;
        #pragma unroll
        for (int k = 0; k < 8; ++k) {
            sl[k] = (int)(((unsigned long long)(unsigned)dd[k] * 1407374884ULL) >> 41); // dst*64/100000
            atomicAdd(&lcnt[sl[k]], 1);
        }
    }
    __syncthreads();
    if (tid < NSLICE) {
        const int c = lcnt[tid];
        lbase[tid] = c ? atomicAdd(&cursor[tid], c) : 0;
        lcnt[tid] = 0;
    }
    __syncthreads();
    if (active) {
        #pragma unroll
        for (int k = 0; k < 8; ++k) {
            const int e   = e0 + k;
            const int ety = (int)(((unsigned long long)(unsigned)e * 1407374884ULL) >> 47);
            const int off = e - ety * N_EDGES;
            const int r   = atomicAdd(&lcnt[sl[k]], 1);
            const int pos = lbase[sl[k]] + r;
            const unsigned lo = (unsigned)ss[k] | ((unsigned)dd[k] << 17);
            const unsigned hi = ((unsigned)dd[k] >> 15) | ((unsigned)ety << 2) | ((unsigned)off << 6);
            rec[pos] = make_uint2(lo, hi);
        }
    }
}

// ---------------- pass 3: XCD/time-phased gather + dot + sigmoid ----------------
// Block -> (slice s, chunk): x = b&7 (XCD), s = x + 8*(b>>11), chunk = (b>>3)&255.
// Each XCD's in-flight dst rows = its 0.4MB slice -> L2-resident.
// Wave = 4 groups x 4 slots = 16 edges; 16 independent loads in flight per thread.
__global__ __launch_bounds__(256) void score_kernel(
    const __half* __restrict__ h16,
    const __half* __restrict__ Wr16,
    const uint2*  __restrict__ rec,
    const int*    __restrict__ cursor,
    float*        __restrict__ out)
{
    const int tid  = threadIdx.x;
    const int lane = tid & 63;
    const int g    = lane >> 4;    // group: edge within slot
    const int gl   = lane & 15;
    const int wid  = tid >> 6;

    const int b     = blockIdx.x;
    const int x     = b & 7;
    const int j     = b >> 3;
    const int s     = x + ((j >> 8) << 3);
    const int chunk = j & 255;
    const int sbase = s << 14;                 // * SLICE_CAP
    const int cnt   = cursor[s] - sbase;       // edges in this slice
    const int e_lo  = (chunk << 6) + (wid << 4);   // 64/block, 16/wave
    if (e_lo >= cnt) return;                   // uniform per wave

    const unsigned col = (unsigned)gl << 3;    // 8 halfs (16B) per lane

    const int i0 = e_lo + g;
    const int i1 = e_lo + 4 + g;
    const int i2 = e_lo + 8 + g;
    const int i3 = e_lo + 12 + g;
    const uint2 r0 = rec[sbase + (i0 < cnt ? i0 : 0)];
    const uint2 r1 = rec[sbase + (i1 < cnt ? i1 : 0)];
    const uint2 r2 = rec[sbase + (i2 < cnt ? i2 : 0)];
    const uint2 r3 = rec[sbase + (i3 < cnt ? i3 : 0)];

    const unsigned s0 = r0.x & 131071u, d0 = ((r0.x >> 17) | (r0.y << 15)) & 131071u;
    const unsigned t0 = (r0.y >> 2) & 15u,  o0 = r0.y >> 6;
    const unsigned s1 = r1.x & 131071u, d1 = ((r1.x >> 17) | (r1.y << 15)) & 131071u;
    const unsigned t1 = (r1.y >> 2) & 15u,  o1 = r1.y >> 6;
    const unsigned s2 = r2.x & 131071u, d2 = ((r2.x >> 17) | (r2.y << 15)) & 131071u;
    const unsigned t2 = (r2.y >> 2) & 15u,  o2 = r2.y >> 6;
    const unsigned s3 = r3.x & 131071u, d3 = ((r3.x >> 17) | (r3.y << 15)) & 131071u;
    const unsigned t3 = (r3.y >> 2) & 15u,  o3 = r3.y >> 6;

    const uint4 Wv0 = *(const uint4*)(Wr16 + ((t0 << 7) + col));
    const uint4 Wv1 = *(const uint4*)(Wr16 + ((t1 << 7) + col));
    const uint4 Wv2 = *(const uint4*)(Wr16 + ((t2 << 7) + col));
    const uint4 Wv3 = *(const uint4*)(Wr16 + ((t3 << 7) + col));
    const uint4 A0 = *(const uint4*)(h16 + ((s0 << 7) + col));
    const uint4 B0 = *(const uint4*)(h16 + ((d0 << 7) + col));
    const uint4 A1 = *(const uint4*)(h16 + ((s1 << 7) + col));
    const uint4 B1 = *(const uint4*)(h16 + ((d1 << 7) + col));
    const uint4 A2 = *(const uint4*)(h16 + ((s2 << 7) + col));
    const uint4 B2 = *(const uint4*)(h16 + ((d2 << 7) + col));
    const uint4 A3 = *(const uint4*)(h16 + ((s3 << 7) + col));
    const uint4 B3 = *(const uint4*)(h16 + ((d3 << 7) + col));

    float p0 = row16_sum(dot_row(A0, B0, Wv0));
    float p1 = row16_sum(dot_row(A1, B1, Wv1));
    float p2 = row16_sum(dot_row(A2, B2, Wv2));
    float p3 = row16_sum(dot_row(A3, B3, Wv3));

    if (gl < 4) {
        const int ii = e_lo + (gl << 2) + g;
        if (ii < cnt) {
            const float    res = (gl == 0) ? p0 : (gl == 1) ? p1 : (gl == 2) ? p2 : p3;
            const unsigned tt  = (gl == 0) ? t0 : (gl == 1) ? t1 : (gl == 2) ? t2 : t3;
            const unsigned oo  = (gl == 0) ? o0 : (gl == 1) ? o1 : (gl == 2) ? o2 : o3;
            out[tt * N_EDGES + oo] = 1.0f / (1.0f + __expf(-res));
        }
    }
}

// ---------------- legacy direct-f16 path (ws too small for sort buffers) ----------------
__global__ __launch_bounds__(256) void convert_legacy_kernel(
    const float* __restrict__ h, const float* __restrict__ W,
    __half* __restrict__ h16, __half* __restrict__ W16)
{
    const size_t i = ((size_t)blockIdx.x * 256 + threadIdx.x) * 8;
    const float4 f0 = *(const float4*)(h + i);
    const float4 f1 = *(const float4*)(h + i + 4);
    union { uint4 u; __half2 p[4]; } pk;
    pk.p[0] = __floats2half2_rn(f0.x, f0.y);
    pk.p[1] = __floats2half2_rn(f0.z, f0.w);
    pk.p[2] = __floats2half2_rn(f1.x, f1.y);
    pk.p[3] = __floats2half2_rn(f1.z, f1.w);
    *(uint4*)(h16 + i) = pk.u;
    if (blockIdx.x == 0 && threadIdx.x < (N_ETYPES * N_HID / 8)) {
        const size_t j = (size_t)threadIdx.x * 8;
        const float4 g0 = *(const float4*)(W + j);
        const float4 g1 = *(const float4*)(W + j + 4);
        union { uint4 u; __half2 p[4]; } pw;
        pw.p[0] = __floats2half2_rn(g0.x, g0.y);
        pw.p[1] = __floats2half2_rn(g0.z, g0.w);
        pw.p[2] = __floats2half2_rn(g1.x, g1.y);
        pw.p[3] = __floats2half2_rn(g1.z, g1.w);
        *(uint4*)(W16 + j) = pw.u;
    }
}

__global__ __launch_bounds__(256) void distmult_score_f16_kernel(
    const __half* __restrict__ h16,
    const __half* __restrict__ W16,
    const int*    __restrict__ src,
    const int*    __restrict__ dst,
    const int*    __restrict__ rel,
    float*        __restrict__ out)
{
    const int t    = blockIdx.y;
    const int lane = threadIdx.x & 63;
    const int g    = lane >> 4;
    const int gl   = lane & 15;
    const int wid  = threadIdx.x >> 6;
    const int r = rel[t];
    union { uint4 u; h2v p[4]; } uw;
    uw.u = ((const uint4*)(W16 + (size_t)r * N_HID))[gl];
    const int base = t * N_EDGES;
    const int e0   = (blockIdx.x * 4 + wid) * 8;
    const int* sp = src + base + e0 + g;
    const int* dp = dst + base + e0 + g;
    const int s0 = sp[0], s1 = sp[4], d0 = dp[0], d1 = dp[4];
    const unsigned col = (unsigned)gl << 3;
    const uint4 A0 = *(const uint4*)(h16 + (((unsigned)s0 << 7) + col));
    const uint4 B0 = *(const uint4*)(h16 + (((unsigned)d0 << 7) + col));
    const uint4 A1 = *(const uint4*)(h16 + (((unsigned)s1 << 7) + col));
    const uint4 B1 = *(const uint4*)(h16 + (((unsigned)d1 << 7) + col));
    float p0 = row16_sum(dot_row(A0, B0, uw.u));
    float p1 = row16_sum(dot_row(A1, B1, uw.u));
    if (gl < 2) {
        const float res = gl ? p1 : p0;
        const int e = e0 + g + (gl << 2);
        out[base + e] = 1.0f / (1.0f + __expf(-res));
    }
}

// ---------------- fp32 fallback (no workspace) ----------------
__global__ __launch_bounds__(256) void distmult_score_f32_kernel(
    const float* __restrict__ h,
    const float* __restrict__ W,
    const int*   __restrict__ src,
    const int*   __restrict__ dst,
    const int*   __restrict__ rel,
    float*       __restrict__ out)
{
    const int t    = blockIdx.y;
    const int lane = threadIdx.x & 31;
    const int hw   = (blockIdx.x << 3) + (threadIdx.x >> 5);
    const int r = rel[t];
    const float4 w4 = ((const float4*)(W + (size_t)r * N_HID))[lane];
    const long base = (long)t * N_EDGES;
    const int  e0   = hw * EDGES_PER_HW;
    float res = 0.0f;
    #pragma unroll
    for (int k = 0; k < EDGES_PER_HW; ++k) {
        const int e = e0 + k;
        const int s = src[base + e];
        const int d = dst[base + e];
        const float4 a = ((const float4*)(h + (size_t)s * N_HID))[lane];
        const float4 b = ((const float4*)(h + (size_t)d * N_HID))[lane];
        float p = a.x * w4.x * b.x + a.y * w4.y * b.y
                + a.z * w4.z * b.z + a.w * w4.w * b.w;
        p += __shfl_xor(p, 16, 64);
        p += __shfl_xor(p, 8, 64);
        p += __shfl_xor(p, 4, 64);
        p += __shfl_xor(p, 2, 64);
        p += __shfl_xor(p, 1, 64);
        if (lane == k) res = p;
    }
    if (lane < EDGES_PER_HW) {
        out[base + e0 + lane] = 1.0f / (1.0f + __expf(-res));
    }
}

extern "C" void kernel_launch(void* const* d_in, const int* in_sizes, int n_in,
                              void* d_out, int out_size, void* d_ws, size_t ws_size,
                              hipStream_t stream) {
    const float* h   = (const float*)d_in[0];
    const float* W   = (const float*)d_in[1];
    const int*   src = (const int*)d_in[2];
    const int*   dst = (const int*)d_in[3];
    const int*   rel = (const int*)d_in[4];
    float*       out = (float*)d_out;

    const size_t h16_bytes  = (size_t)N_NODES * N_HID * sizeof(__half);   // 25,600,000
    const size_t wr16_bytes = 4096;
    const size_t rec_bytes  = (size_t)NSLICE * SLICE_CAP * 8;             //  8,388,608
    const size_t cur_bytes  = 4096;
    const size_t need_full  = h16_bytes + wr16_bytes + rec_bytes + cur_bytes;
    const size_t need_f16   = h16_bytes + (size_t)N_ETYPES * N_HID * sizeof(__half);

    if (ws_size >= need_full) {
        char* w = (char*)d_ws;
        __half* h16    = (__half*)w;   w += h16_bytes;
        __half* Wr16   = (__half*)w;   w += wr16_bytes;
        uint2*  rec    = (uint2*)w;    w += rec_bytes;
        int*    cursor = (int*)w;

        convert_kernel<<<(int)(((size_t)N_NODES * N_HID) / (256 * 8)), 256, 0, stream>>>(
            h, W, rel, h16, Wr16, cursor);
        scatter_kernel<<<(TOT_EDGES + EPB_SC - 1) / EPB_SC, 256, 0, stream>>>(
            src, dst, cursor, rec);
        score_kernel<<<NSLICE * (SLICE_CAP / 64), 256, 0, stream>>>(
            h16, Wr16, rec, cursor, out);
    } else if (ws_size >= need_f16) {
        __half* h16 = (__half*)d_ws;
        __half* W16 = h16 + (size_t)N_NODES * N_HID;
        convert_legacy_kernel<<<(int)(((size_t)N_NODES * N_HID) / (256 * 8)), 256, 0, stream>>>(
            h, W, h16, W16);
        dim3 grid(N_EDGES / 32, N_ETYPES);
        distmult_score_f16_kernel<<<grid, 256, 0, stream>>>(h16, W16, src, dst, rel, out);
    } else {
        dim3 grid(N_EDGES / (8 * EDGES_PER_HW), N_ETYPES);
        distmult_score_f32_kernel<<<grid, 256, 0, stream>>>(h, W, src, dst, rel, out);
    }
}